// Round 1
// baseline (215.527 us; speedup 1.0000x reference)
//
#include <hip/hip_runtime.h>
#include <hip/hip_bf16.h>

// GAT layer: N=4096 nodes, F_IN=128, F_OUT=64, HEADS=4.
// Kernel 1 (gat_prep): H = X@W^T + b (fp32 vector GEMM), emit bf16 H^T [h][o][m],
//                      s[h][n] = H·a_src, d[h][n] = H·a_dst (fp32).
// Kernel 2 (gat_main): per 16-row tile: build P[n][m] = mask ? exp(lrelu(s_n+d_m)) : 0
//                      directly in MFMA A-fragment registers, accumulate P@H with
//                      mfma_f32_16x16x32_bf16 per head, normalize by per-row sum l,
//                      add self-edge (diagonal) term in epilogue, sum heads, /4.

#define NN 4096
#define FIN 128
#define FOUT 64
#define NH 4

typedef __attribute__((ext_vector_type(8))) short bf16x8;
typedef __attribute__((ext_vector_type(4))) float f32x4;

__device__ __forceinline__ unsigned short f32_bf16(float f) {
    unsigned u = __builtin_bit_cast(unsigned, f);
    u += 0x7fffu + ((u >> 16) & 1u);          // round-to-nearest-even
    return (unsigned short)(u >> 16);
}
__device__ __forceinline__ float bf16_f32(unsigned short h) {
    unsigned u = ((unsigned)h) << 16;
    return __builtin_bit_cast(float, u);
}

// ---------------- Kernel 1: prep ----------------
// grid (128 row-blocks of 32, 4 heads), 256 threads.
// Per-thread micro-tile: 2 rows x 4 cols.
__global__ __launch_bounds__(256) void gat_prep(
    const float* __restrict__ X, const float* __restrict__ W,
    const float* __restrict__ b, const float* __restrict__ att,
    unsigned short* __restrict__ HbfT, float* __restrict__ s_out,
    float* __restrict__ d_out)
{
    const int rb = blockIdx.x;           // 0..127
    const int h  = blockIdx.y;           // 0..3
    const int n0 = rb * 32;
    const int t  = threadIdx.x;          // 0..255

    __shared__ float Xl[32][132];        // 32 rows x 128 (pad to 132), 16.9 KB
    __shared__ float Wt[128][68];        // W[h] transposed [f][o] (pad 64->68), 34.8 KB

    // stage X rows (coalesced float4)
    for (int g = t; g < 32 * 32; g += 256) {
        int row = g >> 5, c4 = g & 31;
        float4 v = *(const float4*)&X[(size_t)(n0 + row) * FIN + c4 * 4];
        *(float4*)&Xl[row][c4 * 4] = v;
    }
    // stage W[h] transposed
    for (int g = t; g < 64 * 32; g += 256) {
        int o = g >> 5, c4 = g & 31;
        float4 v = *(const float4*)&W[((size_t)h * FOUT + o) * FIN + c4 * 4];
        Wt[c4 * 4 + 0][o] = v.x; Wt[c4 * 4 + 1][o] = v.y;
        Wt[c4 * 4 + 2][o] = v.z; Wt[c4 * 4 + 3][o] = v.w;
    }
    __syncthreads();

    const int rg = t >> 4;               // 0..15 -> rows rg*2 .. rg*2+1
    const int og = t & 15;               // cols og*4 .. og*4+3
    float acc[2][4] = {};

    #pragma unroll 4
    for (int f4 = 0; f4 < 32; ++f4) {
        float xv[2][4], wv[4][4];
        #pragma unroll
        for (int i = 0; i < 2; ++i) {
            float4 tmp = *(const float4*)&Xl[rg * 2 + i][f4 * 4];
            xv[i][0] = tmp.x; xv[i][1] = tmp.y; xv[i][2] = tmp.z; xv[i][3] = tmp.w;
        }
        #pragma unroll
        for (int k = 0; k < 4; ++k) {
            float4 tmp = *(const float4*)&Wt[f4 * 4 + k][og * 4];
            wv[k][0] = tmp.x; wv[k][1] = tmp.y; wv[k][2] = tmp.z; wv[k][3] = tmp.w;
        }
        #pragma unroll
        for (int i = 0; i < 2; ++i)
            #pragma unroll
            for (int k = 0; k < 4; ++k)
                #pragma unroll
                for (int jj = 0; jj < 4; ++jj)
                    acc[i][jj] = fmaf(xv[i][k], wv[k][jj], acc[i][jj]);
    }

    // bias
    float bb[4], as_[4], ad_[4];
    #pragma unroll
    for (int jj = 0; jj < 4; ++jj) {
        bb[jj]  = b[h * FOUT + og * 4 + jj];
        as_[jj] = att[h * 2 * FOUT + og * 4 + jj];
        ad_[jj] = att[h * 2 * FOUT + FOUT + og * 4 + jj];
    }
    #pragma unroll
    for (int i = 0; i < 2; ++i)
        #pragma unroll
        for (int jj = 0; jj < 4; ++jj)
            acc[i][jj] += bb[jj];

    // s,d partials then reduce across the 16 lanes sharing the same rows
    float sp[2] = {0.f, 0.f}, dp[2] = {0.f, 0.f};
    #pragma unroll
    for (int i = 0; i < 2; ++i)
        #pragma unroll
        for (int jj = 0; jj < 4; ++jj) {
            sp[i] = fmaf(acc[i][jj], as_[jj], sp[i]);
            dp[i] = fmaf(acc[i][jj], ad_[jj], dp[i]);
        }
    #pragma unroll
    for (int off = 1; off < 16; off <<= 1) {
        #pragma unroll
        for (int i = 0; i < 2; ++i) {
            sp[i] += __shfl_xor(sp[i], off);
            dp[i] += __shfl_xor(dp[i], off);
        }
    }
    if (og == 0) {
        #pragma unroll
        for (int i = 0; i < 2; ++i) {
            int nn = n0 + rg * 2 + i;
            s_out[h * NN + nn] = sp[i];
            d_out[h * NN + nn] = dp[i];
        }
    }

    // store bf16 H transposed: HbfT[h][o][n], 2 consecutive n per thread (ushort2)
    #pragma unroll
    for (int jj = 0; jj < 4; ++jj) {
        int o = og * 4 + jj;
        ushort2 p;
        p.x = f32_bf16(acc[0][jj]);
        p.y = f32_bf16(acc[1][jj]);
        *(ushort2*)&HbfT[((size_t)h * FOUT + o) * NN + n0 + rg * 2] = p;
    }
}

// ---------------- Kernel 2: masked softmax-aggregate ----------------
// grid 256 (16 rows each), 512 threads = 8 waves = 4 heads x 2 K-halves.
__global__ __launch_bounds__(512) void gat_main(
    const int* __restrict__ A, const unsigned short* __restrict__ HbfT,
    const float* __restrict__ s_g, const float* __restrict__ d_g,
    float* __restrict__ out)
{
    const int n0   = blockIdx.x * 16;
    const int tid  = threadIdx.x;
    const int wv   = tid >> 6;           // 0..7
    const int h    = wv & 3;
    const int kh   = wv >> 2;            // K half
    const int lane = tid & 63;
    const int r    = lane & 15;          // A-operand row / B-operand col
    const int q    = lane >> 4;          // quad -> k offset q*8

    __shared__ float out_acc[16][64];    // 4 KB
    __shared__ float l_lds[8][16];
    __shared__ float lfin[4][16];
    __shared__ float wnn_lds[4][16];

    for (int g = tid; g < 16 * 64; g += 512) ((float*)out_acc)[g] = 0.0f;
    __syncthreads();

    const int n = n0 + r;
    const float s_h = s_g[h * NN + n];
    const float* dh = d_g + h * NN;
    const long  arow = (long)n * NN;
    const unsigned short* hb_base = HbfT + ((size_t)h * FOUT + r) * NN;

    f32x4 acc0 = {0,0,0,0}, acc1 = {0,0,0,0}, acc2 = {0,0,0,0}, acc3 = {0,0,0,0};
    float l_part = 0.f;
    const int m0 = kh * 2048 + q * 8;

    #pragma unroll 2
    for (int step = 0; step < 64; ++step) {
        const int mk = m0 + step * 32;
        const int4   a0  = *(const int4*)  &A[arow + mk];
        const int4   a1  = *(const int4*)  &A[arow + mk + 4];
        const float4 dd0 = *(const float4*)&dh[mk];
        const float4 dd1 = *(const float4*)&dh[mk + 4];

        float dv[8] = {dd0.x, dd0.y, dd0.z, dd0.w, dd1.x, dd1.y, dd1.z, dd1.w};
        int   av[8] = {a0.x, a0.y, a0.z, a0.w, a1.x, a1.y, a1.z, a1.w};

        bf16x8 af;
        float lsum = 0.f;
        #pragma unroll
        for (int j = 0; j < 8; ++j) {
            float tt = s_h + dv[j];
            float lr = fmaxf(tt, 0.01f * tt);   // leaky_relu
            float e  = __expf(lr);
            float w  = (av[j] > 0) ? e : 0.0f;  // adjacency mask (diag handled in epilogue)
            lsum += w;
            af[j] = (short)f32_bf16(w);
        }
        l_part += lsum;

        const unsigned short* hb = hb_base + mk;
        bf16x8 b0 = *(const bf16x8*)(hb);
        bf16x8 b1 = *(const bf16x8*)(hb + 16 * NN);
        bf16x8 b2 = *(const bf16x8*)(hb + 32 * NN);
        bf16x8 b3 = *(const bf16x8*)(hb + 48 * NN);
        acc0 = __builtin_amdgcn_mfma_f32_16x16x32_bf16(af, b0, acc0, 0, 0, 0);
        acc1 = __builtin_amdgcn_mfma_f32_16x16x32_bf16(af, b1, acc1, 0, 0, 0);
        acc2 = __builtin_amdgcn_mfma_f32_16x16x32_bf16(af, b2, acc2, 0, 0, 0);
        acc3 = __builtin_amdgcn_mfma_f32_16x16x32_bf16(af, b3, acc3, 0, 0, 0);
    }

    // reduce l across quads (same row r), then across waves via LDS
    l_part += __shfl_xor(l_part, 16);
    l_part += __shfl_xor(l_part, 32);
    if (lane < 16) l_lds[wv][r] = l_part;
    __syncthreads();

    // full denominator per (head,row): both K halves + self-edge weight
    if (wv < 4 && lane < 16) {
        float dvd = dh[n];                       // d[h][n]  (diagonal m == n)
        float tt = s_h + dvd;
        float wdiag = __expf(fmaxf(tt, 0.01f * tt));
        float lf = l_lds[h][r] + l_lds[h + 4][r] + wdiag;
        lfin[h][r] = lf;
        wnn_lds[h][r] = wdiag;
    }
    __syncthreads();

    // scale accumulators by 0.25/l (per C/D row = q*4+reg) and merge across waves
    float scl[4];
    #pragma unroll
    for (int reg = 0; reg < 4; ++reg) scl[reg] = 0.25f / lfin[h][q * 4 + reg];
    #pragma unroll
    for (int reg = 0; reg < 4; ++reg) {
        int rr = q * 4 + reg;
        atomicAdd(&out_acc[rr][ 0 + r], acc0[reg] * scl[reg]);
        atomicAdd(&out_acc[rr][16 + r], acc1[reg] * scl[reg]);
        atomicAdd(&out_acc[rr][32 + r], acc2[reg] * scl[reg]);
        atomicAdd(&out_acc[rr][48 + r], acc3[reg] * scl[reg]);
    }
    __syncthreads();

    // add diagonal contribution and write out (float2, coalesced)
    {
        const int rr = tid >> 5;             // 0..15
        const int o2 = (tid & 31) * 2;       // 0..62
        const int nn = n0 + rr;
        float v0 = out_acc[rr][o2];
        float v1 = out_acc[rr][o2 + 1];
        #pragma unroll
        for (int hh = 0; hh < 4; ++hh) {
            float coef = wnn_lds[hh][rr] * 0.25f / lfin[hh][rr];
            v0 += coef * bf16_f32(HbfT[((size_t)hh * FOUT + o2    ) * NN + nn]);
            v1 += coef * bf16_f32(HbfT[((size_t)hh * FOUT + o2 + 1) * NN + nn]);
        }
        *(float2*)&out[(size_t)nn * FOUT + o2] = make_float2(v0, v1);
    }
}

extern "C" void kernel_launch(void* const* d_in, const int* in_sizes, int n_in,
                              void* d_out, int out_size, void* d_ws, size_t ws_size,
                              hipStream_t stream) {
    const float* X   = (const float*)d_in[0];
    const int*   A   = (const int*)  d_in[1];
    const float* W   = (const float*)d_in[2];
    const float* b   = (const float*)d_in[3];
    const float* att = (const float*)d_in[4];
    float* out = (float*)d_out;

    char* ws = (char*)d_ws;
    unsigned short* HbfT = (unsigned short*)ws;                       // 4*64*4096*2 = 2 MB
    float* s_buf = (float*)(ws + (size_t)NH * FOUT * NN * 2);         // 64 KB
    float* d_buf = s_buf + NH * NN;                                   // 64 KB

    gat_prep<<<dim3(128, 4), 256, 0, stream>>>(X, W, b, att, HbfT, s_buf, d_buf);
    gat_main<<<256, 512, 0, stream>>>(A, HbfT, s_buf, d_buf, out);
}